// Round 6
// baseline (390.790 us; speedup 1.0000x reference)
//
#include <hip/hip_runtime.h>
#include <hip/hip_bf16.h>
#include <stdint.h>

#define BB 8
#define TT 2048
#define DD 512

typedef __attribute__((ext_vector_type(8))) __bf16 bf16x8;
typedef __attribute__((ext_vector_type(4))) float f32x4;
typedef __attribute__((ext_vector_type(8))) unsigned short ushort8_t;

__device__ __forceinline__ unsigned short f2bf(float f) {
    unsigned u = __builtin_bit_cast(unsigned, f);
    unsigned r = u + 0x7fffu + ((u >> 16) & 1u);
    return (unsigned short)(r >> 16);
}

// async global->LDS DMA, 16B per lane. LDS dest must be wave-uniform base + lane*16.
__device__ __forceinline__ void gload_lds16(const unsigned short* g, unsigned short* l) {
    __builtin_amdgcn_global_load_lds(
        (const __attribute__((address_space(1))) void*)g,
        (__attribute__((address_space(3))) void*)l, 16, 0, 0);
}

// ---------------- gates (wave-per-row matvec, all batches at once) ----------------
__global__ __launch_bounds__(256) void gates_mv1(
    const float* __restrict__ aux,
    const float* __restrict__ Wqg, const float* __restrict__ bqg, const float* __restrict__ aq,
    const float* __restrict__ Wkg, const float* __restrict__ bkg, const float* __restrict__ ak,
    const float* __restrict__ Wvg, const float* __restrict__ bvg, const float* __restrict__ av,
    float* __restrict__ h) {
    __shared__ float saux[BB * DD];
    int tid = threadIdx.x;
#pragma unroll
    for (int i = 0; i < 4; i++) {
        int idx = tid + i * 256;
        ((float4*)saux)[idx] = ((const float4*)aux)[idx];
    }
    __syncthreads();
    int wave = (blockIdx.x * 256 + tid) >> 6;  // 0..1535
    int lane = tid & 63;
    int g = wave >> 9, r = wave & 511;
    const float* W    = (g == 0) ? Wqg : (g == 1) ? Wkg : Wvg;
    const float* bias = (g == 0) ? bqg : (g == 1) ? bkg : bvg;
    const float* alpha = (g == 0) ? aq : (g == 1) ? ak : av;
    const float4* Wrow = (const float4*)(W + (size_t)r * DD);
    float acc[BB];
#pragma unroll
    for (int b = 0; b < BB; b++) acc[b] = 0.f;
#pragma unroll
    for (int c = 0; c < 2; c++) {
        float4 w4 = Wrow[lane + c * 64];
#pragma unroll
        for (int b = 0; b < BB; b++) {
            float4 a4 = ((const float4*)(saux + b * DD))[lane + c * 64];
            acc[b] += w4.x * a4.x + w4.y * a4.y + w4.z * a4.z + w4.w * a4.w;
        }
    }
#pragma unroll
    for (int b = 0; b < BB; b++) {
#pragma unroll
        for (int s = 1; s < 64; s <<= 1) acc[b] += __shfl_xor(acc[b], s, 64);
    }
    if (lane == 0) {
        float bi = bias[r], a = alpha[0];
#pragma unroll
        for (int b = 0; b < BB; b++) {
            float v = acc[b] + bi;
            v = (v >= 0.f) ? v : a * v;
            h[(g * BB + b) * DD + r] = v;
        }
    }
}

__global__ __launch_bounds__(512) void gates_norm(
    const float* __restrict__ h,
    const float* __restrict__ gq, const float* __restrict__ betaq,
    const float* __restrict__ gk, const float* __restrict__ betak,
    const float* __restrict__ gv, const float* __restrict__ betav,
    float* __restrict__ qgate, float* __restrict__ kgate, float* __restrict__ vg) {
    int g = blockIdx.x >> 3, b = blockIdx.x & 7, tid = threadIdx.x;
    __shared__ float red[DD], red2[DD];
    float hv = h[(g * BB + b) * DD + tid];
    red[tid] = hv; red2[tid] = hv * hv;
    __syncthreads();
    for (int s = 256; s > 0; s >>= 1) {
        if (tid < s) { red[tid] += red[tid + s]; red2[tid] += red2[tid + s]; }
        __syncthreads();
    }
    float mu = red[0] * (1.f / DD);
    float var = red2[0] * (1.f / DD) - mu * mu;
    const float* gg = (g == 0) ? gq : (g == 1) ? gk : gv;
    const float* be = (g == 0) ? betaq : (g == 1) ? betak : betav;
    float val = (hv - mu) * rsqrtf(var + 1e-5f) * gg[tid] + be[tid];
    float sg = 1.f / (1.f + expf(-val));
    float* outp = (g == 0) ? qgate : (g == 1) ? kgate : vg;
    outp[b * DD + tid] = sg;
}

__global__ __launch_bounds__(256) void gates_mv2(
    const float* __restrict__ vg,
    const float* __restrict__ Wsig, const float* __restrict__ bsig,
    const float* __restrict__ Wtan, const float* __restrict__ btan,
    float* __restrict__ vgate) {
    __shared__ float svg[BB * DD];
    int tid = threadIdx.x;
#pragma unroll
    for (int i = 0; i < 4; i++) {
        int idx = tid + i * 256;
        ((float4*)svg)[idx] = ((const float4*)vg)[idx];
    }
    __syncthreads();
    int r = (blockIdx.x * 256 + tid) >> 6;  // 0..511
    int lane = tid & 63;
    const float4* Ws = (const float4*)(Wsig + (size_t)r * DD);
    const float4* Wt = (const float4*)(Wtan + (size_t)r * DD);
    float as_[BB], at_[BB];
#pragma unroll
    for (int b = 0; b < BB; b++) { as_[b] = 0.f; at_[b] = 0.f; }
#pragma unroll
    for (int c = 0; c < 2; c++) {
        float4 w1 = Ws[lane + c * 64];
        float4 w2 = Wt[lane + c * 64];
#pragma unroll
        for (int b = 0; b < BB; b++) {
            float4 a4 = ((const float4*)(svg + b * DD))[lane + c * 64];
            as_[b] += w1.x * a4.x + w1.y * a4.y + w1.z * a4.z + w1.w * a4.w;
            at_[b] += w2.x * a4.x + w2.y * a4.y + w2.z * a4.z + w2.w * a4.w;
        }
    }
#pragma unroll
    for (int b = 0; b < BB; b++) {
#pragma unroll
        for (int s = 1; s < 64; s <<= 1) {
            as_[b] += __shfl_xor(as_[b], s, 64);
            at_[b] += __shfl_xor(at_[b], s, 64);
        }
    }
    if (lane == 0) {
        float b1 = bsig[r], b2 = btan[r];
#pragma unroll
        for (int b = 0; b < BB; b++) {
            float s1 = 1.f / (1.f + expf(-(as_[b] + b1)));
            float s2 = tanhf(at_[b] + b2);
            vgate[b * DD + r] = s1 * s2;
        }
    }
}

// ---------------- fused elementwise prep ----------------
// blocks [0,8192): query->bf16 (float4 -> ushort4)
// blocks [8192,8448): Wq->bf16
// blocks [8448,10496): value -> kb + vbT, 64x64 tiles, 16B vector stores.
__global__ __launch_bounds__(256) void convert_kernel(
    const float* __restrict__ query, const float* __restrict__ Wq,
    const float* __restrict__ value,
    const float* __restrict__ kgate, const float* __restrict__ vgate,
    unsigned short* __restrict__ queryb, unsigned short* __restrict__ Wqb,
    unsigned short* __restrict__ kb, unsigned short* __restrict__ vbT) {
    __shared__ float tileF[64][65];
    int bi = blockIdx.x, tid = threadIdx.x;
    if (bi < 8192) {
        int idx = bi * 256 + tid;
        float4 q4 = ((const float4*)query)[idx];
        ushort4 oq;
        oq.x = f2bf(q4.x); oq.y = f2bf(q4.y); oq.z = f2bf(q4.z); oq.w = f2bf(q4.w);
        ((ushort4*)queryb)[idx] = oq;
    } else if (bi < 8448) {
        int idx = (bi - 8192) * 256 + tid;
        float4 w4 = ((const float4*)Wq)[idx];
        ushort4 o;
        o.x = f2bf(w4.x); o.y = f2bf(w4.y); o.z = f2bf(w4.z); o.w = f2bf(w4.w);
        ((ushort4*)Wqb)[idx] = o;
    } else {
        int vb = bi - 8448;                 // 0..2047
        int tIdx = vb & 31, dIdx = (vb >> 5) & 7, b = vb >> 8;
        int t0 = tIdx * 64, d0 = dIdx * 64;
        int row = tid >> 2;                 // 0..63
        int cg = tid & 3;                   // 16-element column group
        float v[16], kgv[16];
        const float* src = &value[((size_t)b * TT + t0 + row) * DD + d0 + cg * 16];
#pragma unroll
        for (int j = 0; j < 4; j++) {
            float4 f = ((const float4*)src)[j];
            v[j * 4 + 0] = f.x; v[j * 4 + 1] = f.y; v[j * 4 + 2] = f.z; v[j * 4 + 3] = f.w;
            float4 g = *(const float4*)&kgate[b * DD + d0 + cg * 16 + j * 4];
            kgv[j * 4 + 0] = g.x; kgv[j * 4 + 1] = g.y; kgv[j * 4 + 2] = g.z; kgv[j * 4 + 3] = g.w;
        }
        ushort8_t kb8[2];
#pragma unroll
        for (int h = 0; h < 2; h++)
#pragma unroll
            for (int j = 0; j < 8; j++)
                kb8[h][j] = f2bf(v[h * 8 + j] * kgv[h * 8 + j]);
        unsigned short* kdst = &kb[((size_t)b * TT + t0 + row) * DD + d0 + cg * 16];
        *(ushort8_t*)&kdst[0] = kb8[0];
        *(ushort8_t*)&kdst[8] = kb8[1];
#pragma unroll
        for (int j = 0; j < 16; j++) tileF[row][cg * 16 + j] = v[j];
        __syncthreads();
        int d = row;  // transposed ownership
        float g = vgate[b * DD + d0 + d];
        ushort8_t o8[2];
#pragma unroll
        for (int h = 0; h < 2; h++)
#pragma unroll
            for (int j = 0; j < 8; j++)
                o8[h][j] = f2bf(tileF[cg * 16 + h * 8 + j][d] * g);
        unsigned short* vdst = &vbT[((size_t)b * DD + d0 + d) * TT + t0 + cg * 16];
        *(ushort8_t*)&vdst[0] = o8[0];
        *(ushort8_t*)&vdst[8] = o8[1];
    }
}

// ---------------- GEMM core (128x128 tile, BK=32, 4 waves, double-buffered) ----------------
#define STAGE_AB(BUF, K0)                                                                 \
    _Pragma("unroll") for (int i = 0; i < 2; i++) {                                       \
        int idx = tid * 8 + i * 2048;                                                     \
        int r = idx >> 5;                                                                 \
        int cg = ((idx >> 3) & 3) ^ ((r >> 1) & 3);                                       \
        gload_lds16(&Ap_[(size_t)r * lda_ + (K0) + cg * 8], &As[BUF][idx]);               \
        gload_lds16(&Bp_[(size_t)r * ldb_ + (K0) + cg * 8], &Bs[BUF][idx]);               \
    }

#define GEMM_CORE(APTR, ALDA, BPTR, BLDA, KSTART, KEND)                                   \
    __shared__ __align__(16) unsigned short As[2][128 * 32];                              \
    __shared__ __align__(16) unsigned short Bs[2][128 * 32];                              \
    const unsigned short* Ap_ = (APTR);                                                   \
    const unsigned short* Bp_ = (BPTR);                                                   \
    const int lda_ = (ALDA), ldb_ = (BLDA);                                               \
    int tid = threadIdx.x;                                                                \
    int lane = tid & 63, wid = tid >> 6;                                                  \
    int wm = (wid >> 1) * 64, wn = (wid & 1) * 64;                                        \
    int lm = lane & 15, quad = lane >> 4;                                                 \
    f32x4 acc[4][4];                                                                      \
    _Pragma("unroll") for (int im = 0; im < 4; im++)                                      \
        _Pragma("unroll") for (int in = 0; in < 4; in++)                                  \
            acc[im][in] = (f32x4){0.f, 0.f, 0.f, 0.f};                                    \
    STAGE_AB(0, (KSTART))                                                                 \
    int cur_ = 0;                                                                         \
    for (int k0 = (KSTART); k0 < (KEND); k0 += 32) {                                      \
        __syncthreads();                                                                  \
        if (k0 + 32 < (KEND)) { STAGE_AB(cur_ ^ 1, k0 + 32) }                             \
        bf16x8 af[4], bf_[4];                                                             \
        _Pragma("unroll") for (int i = 0; i < 4; i++) {                                   \
            int row = wm + i * 16 + lm;                                                   \
            af[i] = *(const bf16x8*)&As[cur_][row * 32 + (quad ^ ((row >> 1) & 3)) * 8];  \
        }                                                                                 \
        _Pragma("unroll") for (int i = 0; i < 4; i++) {                                   \
            int row = wn + i * 16 + lm;                                                   \
            bf_[i] = *(const bf16x8*)&Bs[cur_][row * 32 + (quad ^ ((row >> 1) & 3)) * 8]; \
        }                                                                                 \
        _Pragma("unroll") for (int im = 0; im < 4; im++)                                  \
            _Pragma("unroll") for (int in = 0; in < 4; in++)                              \
                acc[im][in] = __builtin_amdgcn_mfma_f32_16x16x32_bf16(af[im], bf_[in],    \
                                                                     acc[im][in], 0, 0, 0);\
        cur_ ^= 1;                                                                        \
    }

// q = (queryb @ Wqb^T + bq) * qgate  -> bf16 qb
__global__ __launch_bounds__(256) void qgemm_kernel(
    const unsigned short* __restrict__ Amat, const unsigned short* __restrict__ Bmat,
    const float* __restrict__ bq, const float* __restrict__ qgate,
    unsigned short* __restrict__ qb) {
    int m0 = blockIdx.x * 128, n0 = blockIdx.y * 128;
    const unsigned short* Ap = Amat + (size_t)m0 * DD;
    const unsigned short* Bp = Bmat + (size_t)n0 * DD;
    GEMM_CORE(Ap, DD, Bp, DD, 0, DD)
    int b = m0 >> 11;
#pragma unroll
    for (int im = 0; im < 4; im++) {
        int row = m0 + wm + im * 16 + quad * 4;
#pragma unroll
        for (int in = 0; in < 4; in++) {
            int col = n0 + wn + in * 16 + lm;
            float bias = bq[col];
            float g = qgate[b * DD + col];
#pragma unroll
            for (int r = 0; r < 4; r++) {
                float v = (acc[im][in][r] + bias) * g;
                qb[(size_t)(row + r) * DD + col] = f2bf(v);
            }
        }
    }
}

// ---------------- FUSED attention v4: one strip per block, 2 blocks/CU ----------------
// Round-5 failure was grid-limited occupancy: 256 blocks = 1 block/CU, 2 waves/SIMD —
// TLP, not ILP, was the missing latency cover (VGPR/LDS would allow 2 blocks/CU).
// v4: grid = 64 strips x 8 batches = 512 blocks. LPT dispatch (strip = 63 - bid>>3):
// 8-macro strips launch first, cheap strips backfill -> ~9 macro-units per CU.
// __launch_bounds__(512,4) pins VGPR <= 128 so 2 blocks/CU is guaranteed.
// K ring depth-2 (TLP now does the hiding); V ring depth-2 as before.
__global__ __launch_bounds__(512, 4) void attn_kernel(
    const unsigned short* __restrict__ qb, const unsigned short* __restrict__ kb,
    const unsigned short* __restrict__ vbT, const int* __restrict__ input_len,
    float* __restrict__ out) {
    int bid = blockIdx.x;
    int strip = 63 - (bid >> 3);         // LPT: biggest strips dispatch first
    int b = bid & 7;                     // XCD-pinned batch
    int L = input_len[b];
    int tid = threadIdx.x;
    int lane = tid & 63, w = tid >> 6;   // wave 0..7
    int lm = lane & 15, quad = lane >> 4;
    const size_t bTT = (size_t)b * TT;
    const float scale = 0.044194173824159216f;  // 1/sqrt(512)

    __shared__ __align__(16) unsigned short Qs[32 * 512];   // 32 KB, strip-resident
    __shared__ __align__(16) unsigned short Ps[32 * 256];   // 16 KB
    __shared__ float rs_lds[32];

    // wave-private bases: K rows [w*32, w*32+32), V (n) rows [w*64, w*64+64)
    const unsigned short* kw = kb + (bTT + (size_t)w * 32) * DD;
    const unsigned short* vw = vbT + ((size_t)b * DD + (size_t)w * 64) * TT;

    int t0 = strip * 32;
    int nk = (strip >> 3) + 1;           // macro kv-tiles of 256

    // stage Q strip: 32 rows x 512 (row=idx>>6, 64 chunks/row, 3-bit XOR)
#pragma unroll
    for (int i_ = 0; i_ < 4; i_++) {
        int idx_ = tid + i_ * 512;
        int r_ = idx_ >> 6, c_ = idx_ & 63;
        int gc_ = (c_ & 56) | ((c_ ^ r_) & 7);
        gload_lds16(&qb[(bTT + t0 + r_) * DD + gc_ * 8], &Qs[idx_ * 8]);
    }
    if (tid < 32) rs_lds[tid] = 0.f;
    __syncthreads();  // Qs ready (drains the DMA)

    f32x4 oacc[2][4];
#pragma unroll
    for (int mi = 0; mi < 2; mi++)
#pragma unroll
        for (int ni = 0; ni < 4; ni++) oacc[mi][ni] = (f32x4){0.f, 0.f, 0.f, 0.f};
    float rsum[2][4];
#pragma unroll
    for (int mi = 0; mi < 2; mi++)
#pragma unroll
        for (int r = 0; r < 4; r++) rsum[mi][r] = 0.f;

#pragma unroll 1
    for (int m = 0; m < nk; m++) {
        int kv0 = m * 256;
        const unsigned short* kwm = kw + (size_t)kv0 * DD;
        f32x4 sacc[2][2];
#pragma unroll
        for (int mi = 0; mi < 2; mi++)
#pragma unroll
            for (int ni = 0; ni < 2; ni++) sacc[mi][ni] = (f32x4){0.f, 0.f, 0.f, 0.f};

        // ---- S phase: 16 stages (stage st: d-chunk st*32), depth-2 K ring ----
        bf16x8 bk[2][2];
#pragma unroll
        for (int st = 0; st < 2; st++)
#pragma unroll
            for (int ni = 0; ni < 2; ni++)
                bk[st][ni] = *(const bf16x8*)&kwm[(size_t)(ni * 16 + lm) * DD +
                                                  st * 32 + quad * 8];
#pragma unroll
        for (int st = 0; st < 16; st++) {
            bf16x8 aq[2];
#pragma unroll
            for (int mi = 0; mi < 2; mi++) {
                int row = mi * 16 + lm;
                int c = st * 4 + quad;
                int sc = (c & 56) | ((c ^ row) & 7);
                aq[mi] = *(const bf16x8*)&Qs[(row << 9) + sc * 8];
            }
#pragma unroll
            for (int mi = 0; mi < 2; mi++)
#pragma unroll
                for (int ni = 0; ni < 2; ni++)
                    sacc[mi][ni] = __builtin_amdgcn_mfma_f32_16x16x32_bf16(
                        aq[mi], bk[st & 1][ni], sacc[mi][ni], 0, 0, 0);
            if (st < 14) {
#pragma unroll
                for (int ni = 0; ni < 2; ni++)
                    bk[st & 1][ni] = *(const bf16x8*)&kwm[(size_t)(ni * 16 + lm) * DD +
                                                          (st + 2) * 32 + quad * 8];
            }
        }

        // ---- early V prologue (independent of Ps; barrier wait absorbs latency) ----
        bf16x8 vv[2][4];
#pragma unroll
        for (int kc = 0; kc < 2; kc++)
#pragma unroll
            for (int ni = 0; ni < 4; ni++)
                vv[kc][ni] = *(const bf16x8*)&vw[(size_t)(ni * 16 + lm) * TT +
                                                 kv0 + kc * 32 + quad * 8];

        __syncthreads();  // all waves done reading Ps of previous macro
        // ---- exp + causal mask -> Ps, rowsum accumulate ----
#pragma unroll
        for (int mi = 0; mi < 2; mi++)
#pragma unroll
            for (int ni = 0; ni < 2; ni++)
#pragma unroll
                for (int r = 0; r < 4; r++) {
                    int trow = mi * 16 + quad * 4 + r;
                    int t = t0 + trow;
                    int e = w * 32 + ni * 16 + lm;     // local kv col
                    int s = kv0 + e;
                    float pv = (s <= t) ? expf(sacc[mi][ni][r] * scale) : 0.f;
                    rsum[mi][r] += pv;
                    int c = e >> 3, o = e & 7;
                    int sc = (c & 24) | ((c ^ trow) & 7);
                    Ps[trow * 256 + sc * 8 + o] = f2bf(pv);
                }
        __syncthreads();  // Ps visible

        // ---- PV phase: 8 stages, depth-2 V ring ----
#pragma unroll
        for (int kc = 0; kc < 8; kc++) {
            bf16x8 pa[2];
#pragma unroll
            for (int mi = 0; mi < 2; mi++) {
                int row = mi * 16 + lm;
                int c = kc * 4 + quad;
                int sc = (c & 24) | ((c ^ row) & 7);
                pa[mi] = *(const bf16x8*)&Ps[row * 256 + sc * 8];
            }
#pragma unroll
            for (int mi = 0; mi < 2; mi++)
#pragma unroll
                for (int ni = 0; ni < 4; ni++)
                    oacc[mi][ni] = __builtin_amdgcn_mfma_f32_16x16x32_bf16(
                        pa[mi], vv[kc & 1][ni], oacc[mi][ni], 0, 0, 0);
            if (kc < 6) {
#pragma unroll
                for (int ni = 0; ni < 4; ni++)
                    vv[kc & 1][ni] = *(const bf16x8*)&vw[(size_t)(ni * 16 + lm) * TT +
                                                         kv0 + (kc + 2) * 32 + quad * 8];
            }
        }
    }

    // ---- strip epilogue: rowsum reduce, normalize, store ----
    __syncthreads();
#pragma unroll
    for (int mi = 0; mi < 2; mi++)
#pragma unroll
        for (int r = 0; r < 4; r++) {
            float v = rsum[mi][r];
            v += __shfl_xor(v, 1, 64);
            v += __shfl_xor(v, 2, 64);
            v += __shfl_xor(v, 4, 64);
            v += __shfl_xor(v, 8, 64);
            if (lm == 0) atomicAdd(&rs_lds[mi * 16 + quad * 4 + r], v);
        }
    __syncthreads();
#pragma unroll
    for (int mi = 0; mi < 2; mi++)
#pragma unroll
        for (int r = 0; r < 4; r++) {
            int trow = mi * 16 + quad * 4 + r;
            int t = t0 + trow;
            float inv = 1.f / rs_lds[trow];
            bool valid = (t < L);
#pragma unroll
            for (int ni = 0; ni < 4; ni++) {
                int n = w * 64 + ni * 16 + lm;
                float o = valid ? oacc[mi][ni][r] * inv : 0.f;
                out[(bTT + t) * DD + n] = o;
            }
        }
}

// ---------------- launch ----------------
extern "C" void kernel_launch(void* const* d_in, const int* in_sizes, int n_in,
                              void* d_out, int out_size, void* d_ws, size_t ws_size,
                              hipStream_t stream) {
    const float* query = (const float*)d_in[0];
    const float* value = (const float*)d_in[1];
    const float* aux   = (const float*)d_in[2];
    const int*   ilen  = (const int*)d_in[3];
    const float* Wq    = (const float*)d_in[4];
    const float* bq    = (const float*)d_in[5];
    const float* Wqg   = (const float*)d_in[6];
    const float* bqg   = (const float*)d_in[7];
    const float* aq    = (const float*)d_in[8];
    const float* gq    = (const float*)d_in[9];
    const float* betaq = (const float*)d_in[10];
    const float* Wkg   = (const float*)d_in[11];
    const float* bkg   = (const float*)d_in[12];
    const float* ak    = (const float*)d_in[13];
    const float* gk    = (const float*)d_in[14];
    const float* betak = (const float*)d_in[15];
    const float* Wvg   = (const float*)d_in[16];
    const float* bvg   = (const float*)d_in[17];
    const float* av    = (const float*)d_in[18];
    const float* gv    = (const float*)d_in[19];
    const float* betav = (const float*)d_in[20];
    const float* Wsig  = (const float*)d_in[21];
    const float* bsig  = (const float*)d_in[22];
    const float* Wtan  = (const float*)d_in[23];
    const float* btan  = (const float*)d_in[24];

    char* ws = (char*)d_ws;
    float* qgate          = (float*)(ws + 0);          // 16 KB
    float* kgate          = (float*)(ws + 16384);      // 16 KB
    float* vgate          = (float*)(ws + 32768);      // 16 KB
    unsigned short* Wqb   = (unsigned short*)(ws + 114688);    // 512 KB
    unsigned short* queryb= (unsigned short*)(ws + 638976);    // 16 MB
    unsigned short* qb    = (unsigned short*)(ws + 17416192);  // 16 MB
    unsigned short* kb    = (unsigned short*)(ws + 34193408);  // 16 MB
    unsigned short* vbT   = (unsigned short*)(ws + 50970624);  // 16 MB
    // gate scratch (transient, used only before convert_kernel)
    float* hbuf           = (float*)(ws + 67747840);           // 48 KB
    float* vg             = (float*)(ws + 67747840 + 49152);   // 16 KB

    gates_mv1<<<384, 256, 0, stream>>>(aux, Wqg, bqg, aq, Wkg, bkg, ak, Wvg, bvg, av, hbuf);
    gates_norm<<<24, 512, 0, stream>>>(hbuf, gq, betaq, gk, betak, gv, betav,
                                       qgate, kgate, vg);
    gates_mv2<<<128, 256, 0, stream>>>(vg, Wsig, bsig, Wtan, btan, vgate);

    convert_kernel<<<10496, 256, 0, stream>>>(query, Wq, value, kgate, vgate,
                                              queryb, Wqb, kb, vbT);
    qgemm_kernel<<<dim3((BB * TT) / 128, DD / 128), 256, 0, stream>>>(queryb, Wqb, bq, qgate, qb);
    attn_kernel<<<512, 512, 0, stream>>>(qb, kb, vbT, ilen, (float*)d_out);
}

// Round 7
// 259.501 us; speedup vs baseline: 1.5059x; 1.5059x over previous
//
#include <hip/hip_runtime.h>
#include <hip/hip_bf16.h>
#include <stdint.h>

#define BB 8
#define TT 2048
#define DD 512

typedef __attribute__((ext_vector_type(8))) __bf16 bf16x8;
typedef __attribute__((ext_vector_type(4))) float f32x4;
typedef __attribute__((ext_vector_type(8))) unsigned short ushort8_t;

__device__ __forceinline__ unsigned short f2bf(float f) {
    unsigned u = __builtin_bit_cast(unsigned, f);
    unsigned r = u + 0x7fffu + ((u >> 16) & 1u);
    return (unsigned short)(r >> 16);
}

// async global->LDS DMA, 16B per lane. LDS dest must be wave-uniform base + lane*16.
__device__ __forceinline__ void gload_lds16(const unsigned short* g, unsigned short* l) {
    __builtin_amdgcn_global_load_lds(
        (const __attribute__((address_space(1))) void*)g,
        (__attribute__((address_space(3))) void*)l, 16, 0, 0);
}

// ---------------- gates (wave-per-row matvec, all batches at once) ----------------
__global__ __launch_bounds__(256) void gates_mv1(
    const float* __restrict__ aux,
    const float* __restrict__ Wqg, const float* __restrict__ bqg, const float* __restrict__ aq,
    const float* __restrict__ Wkg, const float* __restrict__ bkg, const float* __restrict__ ak,
    const float* __restrict__ Wvg, const float* __restrict__ bvg, const float* __restrict__ av,
    float* __restrict__ h) {
    __shared__ float saux[BB * DD];
    int tid = threadIdx.x;
#pragma unroll
    for (int i = 0; i < 4; i++) {
        int idx = tid + i * 256;
        ((float4*)saux)[idx] = ((const float4*)aux)[idx];
    }
    __syncthreads();
    int wave = (blockIdx.x * 256 + tid) >> 6;  // 0..1535
    int lane = tid & 63;
    int g = wave >> 9, r = wave & 511;
    const float* W    = (g == 0) ? Wqg : (g == 1) ? Wkg : Wvg;
    const float* bias = (g == 0) ? bqg : (g == 1) ? bkg : bvg;
    const float* alpha = (g == 0) ? aq : (g == 1) ? ak : av;
    const float4* Wrow = (const float4*)(W + (size_t)r * DD);
    float acc[BB];
#pragma unroll
    for (int b = 0; b < BB; b++) acc[b] = 0.f;
#pragma unroll
    for (int c = 0; c < 2; c++) {
        float4 w4 = Wrow[lane + c * 64];
#pragma unroll
        for (int b = 0; b < BB; b++) {
            float4 a4 = ((const float4*)(saux + b * DD))[lane + c * 64];
            acc[b] += w4.x * a4.x + w4.y * a4.y + w4.z * a4.z + w4.w * a4.w;
        }
    }
#pragma unroll
    for (int b = 0; b < BB; b++) {
#pragma unroll
        for (int s = 1; s < 64; s <<= 1) acc[b] += __shfl_xor(acc[b], s, 64);
    }
    if (lane == 0) {
        float bi = bias[r], a = alpha[0];
#pragma unroll
        for (int b = 0; b < BB; b++) {
            float v = acc[b] + bi;
            v = (v >= 0.f) ? v : a * v;
            h[(g * BB + b) * DD + r] = v;
        }
    }
}

__global__ __launch_bounds__(512) void gates_norm(
    const float* __restrict__ h,
    const float* __restrict__ gq, const float* __restrict__ betaq,
    const float* __restrict__ gk, const float* __restrict__ betak,
    const float* __restrict__ gv, const float* __restrict__ betav,
    float* __restrict__ qgate, float* __restrict__ kgate, float* __restrict__ vg) {
    int g = blockIdx.x >> 3, b = blockIdx.x & 7, tid = threadIdx.x;
    __shared__ float red[DD], red2[DD];
    float hv = h[(g * BB + b) * DD + tid];
    red[tid] = hv; red2[tid] = hv * hv;
    __syncthreads();
    for (int s = 256; s > 0; s >>= 1) {
        if (tid < s) { red[tid] += red[tid + s]; red2[tid] += red2[tid + s]; }
        __syncthreads();
    }
    float mu = red[0] * (1.f / DD);
    float var = red2[0] * (1.f / DD) - mu * mu;
    const float* gg = (g == 0) ? gq : (g == 1) ? gk : gv;
    const float* be = (g == 0) ? betaq : (g == 1) ? betak : betav;
    float val = (hv - mu) * rsqrtf(var + 1e-5f) * gg[tid] + be[tid];
    float sg = 1.f / (1.f + expf(-val));
    float* outp = (g == 0) ? qgate : (g == 1) ? kgate : vg;
    outp[b * DD + tid] = sg;
}

__global__ __launch_bounds__(256) void gates_mv2(
    const float* __restrict__ vg,
    const float* __restrict__ Wsig, const float* __restrict__ bsig,
    const float* __restrict__ Wtan, const float* __restrict__ btan,
    float* __restrict__ vgate) {
    __shared__ float svg[BB * DD];
    int tid = threadIdx.x;
#pragma unroll
    for (int i = 0; i < 4; i++) {
        int idx = tid + i * 256;
        ((float4*)svg)[idx] = ((const float4*)vg)[idx];
    }
    __syncthreads();
    int r = (blockIdx.x * 256 + tid) >> 6;  // 0..511
    int lane = tid & 63;
    const float4* Ws = (const float4*)(Wsig + (size_t)r * DD);
    const float4* Wt = (const float4*)(Wtan + (size_t)r * DD);
    float as_[BB], at_[BB];
#pragma unroll
    for (int b = 0; b < BB; b++) { as_[b] = 0.f; at_[b] = 0.f; }
#pragma unroll
    for (int c = 0; c < 2; c++) {
        float4 w1 = Ws[lane + c * 64];
        float4 w2 = Wt[lane + c * 64];
#pragma unroll
        for (int b = 0; b < BB; b++) {
            float4 a4 = ((const float4*)(svg + b * DD))[lane + c * 64];
            as_[b] += w1.x * a4.x + w1.y * a4.y + w1.z * a4.z + w1.w * a4.w;
            at_[b] += w2.x * a4.x + w2.y * a4.y + w2.z * a4.z + w2.w * a4.w;
        }
    }
#pragma unroll
    for (int b = 0; b < BB; b++) {
#pragma unroll
        for (int s = 1; s < 64; s <<= 1) {
            as_[b] += __shfl_xor(as_[b], s, 64);
            at_[b] += __shfl_xor(at_[b], s, 64);
        }
    }
    if (lane == 0) {
        float b1 = bsig[r], b2 = btan[r];
#pragma unroll
        for (int b = 0; b < BB; b++) {
            float s1 = 1.f / (1.f + expf(-(as_[b] + b1)));
            float s2 = tanhf(at_[b] + b2);
            vgate[b * DD + r] = s1 * s2;
        }
    }
}

// ---------------- fused elementwise prep (vectorized value path) ----------------
// blocks [0,8192): query->bf16 (float4 -> ushort4)
// blocks [8192,8448): Wq->bf16
// blocks [8448,10496): value -> kb + vbT, 64x64 tiles, 16B vector stores.
__global__ __launch_bounds__(256) void convert_kernel(
    const float* __restrict__ query, const float* __restrict__ Wq,
    const float* __restrict__ value,
    const float* __restrict__ kgate, const float* __restrict__ vgate,
    unsigned short* __restrict__ queryb, unsigned short* __restrict__ Wqb,
    unsigned short* __restrict__ kb, unsigned short* __restrict__ vbT) {
    __shared__ float tileF[64][65];
    int bi = blockIdx.x, tid = threadIdx.x;
    if (bi < 8192) {
        int idx = bi * 256 + tid;
        float4 q4 = ((const float4*)query)[idx];
        ushort4 oq;
        oq.x = f2bf(q4.x); oq.y = f2bf(q4.y); oq.z = f2bf(q4.z); oq.w = f2bf(q4.w);
        ((ushort4*)queryb)[idx] = oq;
    } else if (bi < 8448) {
        int idx = (bi - 8192) * 256 + tid;
        float4 w4 = ((const float4*)Wq)[idx];
        ushort4 o;
        o.x = f2bf(w4.x); o.y = f2bf(w4.y); o.z = f2bf(w4.z); o.w = f2bf(w4.w);
        ((ushort4*)Wqb)[idx] = o;
    } else {
        int vb = bi - 8448;                 // 0..2047
        int tIdx = vb & 31, dIdx = (vb >> 5) & 7, b = vb >> 8;
        int t0 = tIdx * 64, d0 = dIdx * 64;
        int row = tid >> 2;                 // 0..63
        int cg = tid & 3;                   // 16-element column group
        float v[16], kgv[16];
        const float* src = &value[((size_t)b * TT + t0 + row) * DD + d0 + cg * 16];
#pragma unroll
        for (int j = 0; j < 4; j++) {
            float4 f = ((const float4*)src)[j];
            v[j * 4 + 0] = f.x; v[j * 4 + 1] = f.y; v[j * 4 + 2] = f.z; v[j * 4 + 3] = f.w;
            float4 g = *(const float4*)&kgate[b * DD + d0 + cg * 16 + j * 4];
            kgv[j * 4 + 0] = g.x; kgv[j * 4 + 1] = g.y; kgv[j * 4 + 2] = g.z; kgv[j * 4 + 3] = g.w;
        }
        ushort8_t kb8[2];
#pragma unroll
        for (int h = 0; h < 2; h++)
#pragma unroll
            for (int j = 0; j < 8; j++)
                kb8[h][j] = f2bf(v[h * 8 + j] * kgv[h * 8 + j]);
        unsigned short* kdst = &kb[((size_t)b * TT + t0 + row) * DD + d0 + cg * 16];
        *(ushort8_t*)&kdst[0] = kb8[0];
        *(ushort8_t*)&kdst[8] = kb8[1];
#pragma unroll
        for (int j = 0; j < 16; j++) tileF[row][cg * 16 + j] = v[j];
        __syncthreads();
        int d = row;  // transposed ownership
        float g = vgate[b * DD + d0 + d];
        ushort8_t o8[2];
#pragma unroll
        for (int h = 0; h < 2; h++)
#pragma unroll
            for (int j = 0; j < 8; j++)
                o8[h][j] = f2bf(tileF[cg * 16 + h * 8 + j][d] * g);
        unsigned short* vdst = &vbT[((size_t)b * DD + d0 + d) * TT + t0 + cg * 16];
        *(ushort8_t*)&vdst[0] = o8[0];
        *(ushort8_t*)&vdst[8] = o8[1];
    }
}

// ---------------- GEMM core (128x128 tile, BK=32, 4 waves, double-buffered) ----------------
#define STAGE_AB(BUF, K0)                                                                 \
    _Pragma("unroll") for (int i = 0; i < 2; i++) {                                       \
        int idx = tid * 8 + i * 2048;                                                     \
        int r = idx >> 5;                                                                 \
        int cg = ((idx >> 3) & 3) ^ ((r >> 1) & 3);                                       \
        gload_lds16(&Ap_[(size_t)r * lda_ + (K0) + cg * 8], &As[BUF][idx]);               \
        gload_lds16(&Bp_[(size_t)r * ldb_ + (K0) + cg * 8], &Bs[BUF][idx]);               \
    }

#define GEMM_CORE(APTR, ALDA, BPTR, BLDA, KSTART, KEND)                                   \
    __shared__ __align__(16) unsigned short As[2][128 * 32];                              \
    __shared__ __align__(16) unsigned short Bs[2][128 * 32];                              \
    const unsigned short* Ap_ = (APTR);                                                   \
    const unsigned short* Bp_ = (BPTR);                                                   \
    const int lda_ = (ALDA), ldb_ = (BLDA);                                               \
    int tid = threadIdx.x;                                                                \
    int lane = tid & 63, wid = tid >> 6;                                                  \
    int wm = (wid >> 1) * 64, wn = (wid & 1) * 64;                                        \
    int lm = lane & 15, quad = lane >> 4;                                                 \
    f32x4 acc[4][4];                                                                      \
    _Pragma("unroll") for (int im = 0; im < 4; im++)                                      \
        _Pragma("unroll") for (int in = 0; in < 4; in++)                                  \
            acc[im][in] = (f32x4){0.f, 0.f, 0.f, 0.f};                                    \
    STAGE_AB(0, (KSTART))                                                                 \
    int cur_ = 0;                                                                         \
    for (int k0 = (KSTART); k0 < (KEND); k0 += 32) {                                      \
        __syncthreads();                                                                  \
        if (k0 + 32 < (KEND)) { STAGE_AB(cur_ ^ 1, k0 + 32) }                             \
        bf16x8 af[4], bf_[4];                                                             \
        _Pragma("unroll") for (int i = 0; i < 4; i++) {                                   \
            int row = wm + i * 16 + lm;                                                   \
            af[i] = *(const bf16x8*)&As[cur_][row * 32 + (quad ^ ((row >> 1) & 3)) * 8];  \
        }                                                                                 \
        _Pragma("unroll") for (int i = 0; i < 4; i++) {                                   \
            int row = wn + i * 16 + lm;                                                   \
            bf_[i] = *(const bf16x8*)&Bs[cur_][row * 32 + (quad ^ ((row >> 1) & 3)) * 8]; \
        }                                                                                 \
        _Pragma("unroll") for (int im = 0; im < 4; im++)                                  \
            _Pragma("unroll") for (int in = 0; in < 4; in++)                              \
                acc[im][in] = __builtin_amdgcn_mfma_f32_16x16x32_bf16(af[im], bf_[in],    \
                                                                     acc[im][in], 0, 0, 0);\
        cur_ ^= 1;                                                                        \
    }

// q = (queryb @ Wqb^T + bq) * qgate  -> bf16 qb
__global__ __launch_bounds__(256) void qgemm_kernel(
    const unsigned short* __restrict__ Amat, const unsigned short* __restrict__ Bmat,
    const float* __restrict__ bq, const float* __restrict__ qgate,
    unsigned short* __restrict__ qb) {
    int m0 = blockIdx.x * 128, n0 = blockIdx.y * 128;
    const unsigned short* Ap = Amat + (size_t)m0 * DD;
    const unsigned short* Bp = Bmat + (size_t)n0 * DD;
    GEMM_CORE(Ap, DD, Bp, DD, 0, DD)
    int b = m0 >> 11;
#pragma unroll
    for (int im = 0; im < 4; im++) {
        int row = m0 + wm + im * 16 + quad * 4;
#pragma unroll
        for (int in = 0; in < 4; in++) {
            int col = n0 + wn + in * 16 + lm;
            float bias = bq[col];
            float g = qgate[b * DD + col];
#pragma unroll
            for (int r = 0; r < 4; r++) {
                float v = (acc[im][in][r] + bias) * g;
                qb[(size_t)(row + r) * DD + col] = f2bf(v);
            }
        }
    }
}

// P = exp(qb @ kb^T / sqrt(D)) with causal mask; rowsum accumulated.
// P stored PACKED lower-triangular: tile (mt,nt) at slot mt*(mt+1)/2+nt, 128x128
// row-major inside the tile. XCD remap: b = lin&7 pins each batch's qb+kb (~4MB)
// to one XCD's L2 (dispatch order round-robins linear block id across XCDs).
__global__ __launch_bounds__(256) void scores_kernel(
    const unsigned short* __restrict__ qb, const unsigned short* __restrict__ kb,
    unsigned short* __restrict__ P, float* __restrict__ rowsum) {
    int lin = blockIdx.x + 136 * blockIdx.z;   // 0..1087
    int b = lin & 7;
    int idx = lin >> 3;                        // 0..135
    int mt = (int)((sqrtf(8.f * idx + 1.f) - 1.f) * 0.5f);
    while ((mt + 1) * (mt + 2) / 2 <= idx) mt++;
    while (mt * (mt + 1) / 2 > idx) mt--;
    int nt = idx - mt * (mt + 1) / 2;
    int t0 = mt * 128, s0 = nt * 128;
    const unsigned short* Ap = qb + ((size_t)b * TT + t0) * DD;
    const unsigned short* Bp = kb + ((size_t)b * TT + s0) * DD;
    GEMM_CORE(Ap, DD, Bp, DD, 0, DD)
    const float scale = 0.044194173824159216f;  // 1/sqrt(512)
    unsigned short* Ptile = P + ((size_t)b * 136 + (size_t)mt * (mt + 1) / 2 + nt) * 16384;
#pragma unroll
    for (int im = 0; im < 4; im++) {
        int ltb = wm + im * 16 + quad * 4;
        float rs[4] = {0.f, 0.f, 0.f, 0.f};
#pragma unroll
        for (int in = 0; in < 4; in++) {
            int ls = wn + in * 16 + lm;
            int s = s0 + ls;
#pragma unroll
            for (int r = 0; r < 4; r++) {
                float p = (s <= t0 + ltb + r) ? expf(acc[im][in][r] * scale) : 0.f;
                Ptile[(size_t)(ltb + r) * 128 + ls] = f2bf(p);
                rs[r] += p;
            }
        }
#pragma unroll
        for (int r = 0; r < 4; r++) {
            float v = rs[r];
            v += __shfl_xor(v, 1, 64);
            v += __shfl_xor(v, 2, 64);
            v += __shfl_xor(v, 4, 64);
            v += __shfl_xor(v, 8, 64);
            if (lm == 0) atomicAdd(&rowsum[b * TT + t0 + ltb + r], v);
        }
    }
}

// out = (P @ V) / rowsum, zero rows t >= L.
// 64-row m-tiles paired (p, 31-p): uniform 33 K64-steps/block, 512 blocks =
// 2 blocks/CU, double-buffered prefetch. XCD remap pins batch -> XCD for vbT reuse.
__global__ __launch_bounds__(256) void out_kernel(
    const unsigned short* __restrict__ P, const unsigned short* __restrict__ vbT,
    const float* __restrict__ rowsum, const int* __restrict__ input_len,
    float* __restrict__ out) {
    int lin = blockIdx.x + 4 * blockIdx.y + 64 * blockIdx.z;  // 0..511
    int b = lin & 7;
    int rem = lin >> 3;          // 0..63
    int nt = rem & 3;            // n-tile of 128
    int pr = rem >> 2;           // 0..15 pair index
    int n0 = nt * 128;
    int L = input_len[b];

    __shared__ __align__(16) unsigned short As[2][64 * 64];
    __shared__ __align__(16) unsigned short Bs[2][128 * 64];
    int tid = threadIdx.x;
    int lane = tid & 63, wid = tid >> 6;
    int wm = (wid >> 1) * 32, wn = (wid & 1) * 64;  // wave tile 32x64
    int lm = lane & 15, quad = lane >> 4;

#pragma unroll
    for (int half = 0; half < 2; half++) {
        int mt = half ? (31 - pr) : pr;     // 64-row m-tile, 0..31
        int t0 = mt * 64;
        int mt128 = mt >> 1;
        int rowoff = (mt & 1) * 64;
        size_t triBase = ((size_t)b * 136 + (size_t)mt128 * (mt128 + 1) / 2) * 16384;
        int ksteps = mt + 1;                // K64 steps; pair total = 33 for all blocks

        f32x4 acc[2][4];
#pragma unroll
        for (int im = 0; im < 2; im++)
#pragma unroll
            for (int in = 0; in < 4; in++) acc[im][in] = (f32x4){0.f, 0.f, 0.f, 0.f};

#define OUT_STAGE(BUF, KS)                                                              \
        {                                                                               \
            int k0s = (KS) * 64;                                                        \
            int stile = k0s >> 7;                                                       \
            int coloff = k0s & 64;                                                      \
            _Pragma("unroll") for (int i = 0; i < 2; i++) {                             \
                int idx = tid * 8 + i * 2048;                                           \
                int r = idx >> 6;                                                       \
                int c = (idx >> 3) & 7;                                                 \
                int cs = c ^ (r & 7);                                                   \
                const unsigned short* ag = P + triBase + (size_t)stile * 16384 +        \
                                           (size_t)(rowoff + r) * 128 + coloff + cs * 8;\
                gload_lds16(ag, &As[BUF][idx]);                                         \
            }                                                                           \
            _Pragma("unroll") for (int i = 0; i < 4; i++) {                             \
                int idx = tid * 8 + i * 2048;                                           \
                int r = idx >> 6;                                                       \
                int c = (idx >> 3) & 7;                                                 \
                int cs = c ^ (r & 7);                                                   \
                gload_lds16(&vbT[(size_t)(b * DD + n0 + r) * TT + k0s + cs * 8],        \
                            &Bs[BUF][idx]);                                             \
            }                                                                           \
        }

        OUT_STAGE(0, 0)
        int cur = 0;
        for (int ks = 0; ks < ksteps; ks++) {
            __syncthreads();
            if (ks + 1 < ksteps) { OUT_STAGE(cur ^ 1, ks + 1) }
            bf16x8 af[2][2], bf_[4][2];
#pragma unroll
            for (int kk = 0; kk < 2; kk++) {
#pragma unroll
                for (int i = 0; i < 2; i++) {
                    int row = wm + i * 16 + lm;
                    af[i][kk] = *(const bf16x8*)&As[cur][row * 64 + ((kk * 4 + quad) ^ (row & 7)) * 8];
                }
#pragma unroll
                for (int i = 0; i < 4; i++) {
                    int row = wn + i * 16 + lm;
                    bf_[i][kk] = *(const bf16x8*)&Bs[cur][row * 64 + ((kk * 4 + quad) ^ (row & 7)) * 8];
                }
            }
#pragma unroll
            for (int kk = 0; kk < 2; kk++)
#pragma unroll
                for (int im = 0; im < 2; im++)
#pragma unroll
                    for (int in = 0; in < 4; in++)
                        acc[im][in] = __builtin_amdgcn_mfma_f32_16x16x32_bf16(
                            af[im][kk], bf_[in][kk], acc[im][in], 0, 0, 0);
            cur ^= 1;
        }
        // protect LDS buffers from next half's prologue stage
        __syncthreads();
#undef OUT_STAGE

#pragma unroll
        for (int im = 0; im < 2; im++) {
            int tbase = t0 + wm + im * 16 + quad * 4;
#pragma unroll
            for (int r = 0; r < 4; r++) {
                int t = tbase + r;
                float inv = 1.f / rowsum[b * TT + t];
                bool valid = (t < L);
#pragma unroll
                for (int in = 0; in < 4; in++) {
                    int n = n0 + wn + in * 16 + lm;
                    float o = valid ? acc[im][in][r] * inv : 0.f;
                    out[((size_t)b * TT + t) * DD + n] = o;
                }
            }
        }
    }
}

// ---------------- launch ----------------
extern "C" void kernel_launch(void* const* d_in, const int* in_sizes, int n_in,
                              void* d_out, int out_size, void* d_ws, size_t ws_size,
                              hipStream_t stream) {
    const float* query = (const float*)d_in[0];
    const float* value = (const float*)d_in[1];
    const float* aux   = (const float*)d_in[2];
    const int*   ilen  = (const int*)d_in[3];
    const float* Wq    = (const float*)d_in[4];
    const float* bq    = (const float*)d_in[5];
    const float* Wqg   = (const float*)d_in[6];
    const float* bqg   = (const float*)d_in[7];
    const float* aq    = (const float*)d_in[8];
    const float* gq    = (const float*)d_in[9];
    const float* betaq = (const float*)d_in[10];
    const float* Wkg   = (const float*)d_in[11];
    const float* bkg   = (const float*)d_in[12];
    const float* ak    = (const float*)d_in[13];
    const float* gk    = (const float*)d_in[14];
    const float* betak = (const float*)d_in[15];
    const float* Wvg   = (const float*)d_in[16];
    const float* bvg   = (const float*)d_in[17];
    const float* av    = (const float*)d_in[18];
    const float* gv    = (const float*)d_in[19];
    const float* betav = (const float*)d_in[20];
    const float* Wsig  = (const float*)d_in[21];
    const float* bsig  = (const float*)d_in[22];
    const float* Wtan  = (const float*)d_in[23];
    const float* btan  = (const float*)d_in[24];

    char* ws = (char*)d_ws;
    float* qgate          = (float*)(ws + 0);          // 16 KB
    float* kgate          = (float*)(ws + 16384);      // 16 KB
    float* vgate          = (float*)(ws + 32768);      // 16 KB
    float* rowsum         = (float*)(ws + 49152);      // 64 KB
    unsigned short* Wqb   = (unsigned short*)(ws + 114688);    // 512 KB
    unsigned short* queryb= (unsigned short*)(ws + 638976);    // 16 MB
    unsigned short* qb    = (unsigned short*)(ws + 17416192);  // 16 MB
    unsigned short* kb    = (unsigned short*)(ws + 34193408);  // 16 MB
    unsigned short* vbT   = (unsigned short*)(ws + 50970624);  // 16 MB
    unsigned short* P     = (unsigned short*)(ws + 67747840);  // packed tri: 35.7 MB
    // gate scratch overlays the P region (P is written only later, in scores_kernel)
    float* hbuf           = (float*)(ws + 67747840);           // 48 KB
    float* vg             = (float*)(ws + 67747840 + 49152);   // 16 KB

    hipMemsetAsync(rowsum, 0, BB * TT * sizeof(float), stream);

    gates_mv1<<<384, 256, 0, stream>>>(aux, Wqg, bqg, aq, Wkg, bkg, ak, Wvg, bvg, av, hbuf);
    gates_norm<<<24, 512, 0, stream>>>(hbuf, gq, betaq, gk, betak, gv, betav,
                                       qgate, kgate, vg);
    gates_mv2<<<128, 256, 0, stream>>>(vg, Wsig, bsig, Wtan, btan, vgate);

    convert_kernel<<<10496, 256, 0, stream>>>(query, Wq, value, kgate, vgate,
                                              queryb, Wqb, kb, vbT);
    qgemm_kernel<<<dim3((BB * TT) / 128, DD / 128), 256, 0, stream>>>(queryb, Wqb, bq, qgate, qb);
    scores_kernel<<<dim3(136, 1, BB), 256, 0, stream>>>(qb, kb, P, rowsum);
    out_kernel<<<dim3(4, 16, BB), 256, 0, stream>>>(P, vbT, rowsum, ilen, (float*)d_out);
}